// Round 1
// baseline (238.718 us; speedup 1.0000x reference)
//
#include <hip/hip_runtime.h>
#include <hip/hip_bf16.h>
#include <stdint.h>

typedef unsigned short u16;

#define D_INNER 2048
#define D_OUTER 2048
#define MROWS   8192                 // B*S = 2*4096
#define W_ELEMS (D_OUTER * D_INNER)  // 4194304

#define BM 128
#define BN 128
#define BK 64

typedef __attribute__((ext_vector_type(8))) __bf16 bf16x8;
typedef __attribute__((ext_vector_type(4))) float  f32x4;

__device__ __forceinline__ u16 f2bf(float f) {
  union { float f; unsigned u; } v; v.f = f;
  unsigned r = v.u + 0x7fff + ((v.u >> 16) & 1);   // RNE
  return (u16)(r >> 16);
}

// ---------------- 1) sum |w| -> ws double ----------------
__global__ void absmean_kernel(const float* __restrict__ w, double* __restrict__ sum) {
  int tid = blockIdx.x * blockDim.x + threadIdx.x;
  int stride = gridDim.x * blockDim.x;
  float s = 0.f;
  for (int i = tid; i < W_ELEMS / 4; i += stride) {
    float4 v = ((const float4*)w)[i];
    s += fabsf(v.x) + fabsf(v.y) + fabsf(v.z) + fabsf(v.w);
  }
  double d = (double)s;
  for (int off = 32; off; off >>= 1) d += __shfl_down(d, off, 64);
  __shared__ double red[4];
  int lane = threadIdx.x & 63, wv = threadIdx.x >> 6;
  if (lane == 0) red[wv] = d;
  __syncthreads();
  if (threadIdx.x == 0) atomicAdd(sum, red[0] + red[1] + red[2] + red[3]);
}

// ---------------- 2) ternary quantize -> bf16 ----------------
__global__ void quant_kernel(const float* __restrict__ w, const double* __restrict__ sum,
                             u16* __restrict__ wq) {
  float gamma = (float)(*sum * (1.0 / (double)W_ELEMS));
  float inv = 1.0f / (gamma + 1e-8f);
  int tid = blockIdx.x * blockDim.x + threadIdx.x;
  int stride = gridDim.x * blockDim.x;
  for (int i = tid; i < W_ELEMS / 4; i += stride) {
    float4 v = ((const float4*)w)[i];
    ushort4 q;
    q.x = f2bf(fminf(1.f, fmaxf(-1.f, rintf(v.x * inv))));
    q.y = f2bf(fminf(1.f, fmaxf(-1.f, rintf(v.y * inv))));
    q.z = f2bf(fminf(1.f, fmaxf(-1.f, rintf(v.z * inv))));
    q.w = f2bf(fminf(1.f, fmaxf(-1.f, rintf(v.w * inv))));
    ((ushort4*)wq)[i] = q;
  }
}

// ---------------- 3) RMSNorm rows -> bf16 ----------------
__global__ void rmsnorm_kernel(const float* __restrict__ x, const float* __restrict__ g,
                               u16* __restrict__ xn) {
  int row = blockIdx.x;
  const float* xr = x + (size_t)row * D_INNER;
  u16* xo = xn + (size_t)row * D_INNER;
  int t = threadIdx.x;

  float4 v0 = ((const float4*)xr)[t * 2];
  float4 v1 = ((const float4*)xr)[t * 2 + 1];
  float s = v0.x * v0.x + v0.y * v0.y + v0.z * v0.z + v0.w * v0.w
          + v1.x * v1.x + v1.y * v1.y + v1.z * v1.z + v1.w * v1.w;
  for (int off = 32; off; off >>= 1) s += __shfl_down(s, off, 64);
  __shared__ float red[4];
  int lane = t & 63, wv = t >> 6;
  if (lane == 0) red[wv] = s;
  __syncthreads();
  float total = red[0] + red[1] + red[2] + red[3];
  float invr = 1.0f / sqrtf(total * (1.0f / (float)D_INNER) + 1e-6f);

  const float4* gr = (const float4*)g;
  float4 g0 = gr[t * 2], g1 = gr[t * 2 + 1];
  ushort4 o0, o1;
  o0.x = f2bf(v0.x * invr * g0.x); o0.y = f2bf(v0.y * invr * g0.y);
  o0.z = f2bf(v0.z * invr * g0.z); o0.w = f2bf(v0.w * invr * g0.w);
  o1.x = f2bf(v1.x * invr * g1.x); o1.y = f2bf(v1.y * invr * g1.y);
  o1.z = f2bf(v1.z * invr * g1.z); o1.w = f2bf(v1.w * invr * g1.w);
  ((ushort4*)xo)[t * 2] = o0;
  ((ushort4*)xo)[t * 2 + 1] = o1;
}

// ---------------- 4) GEMM  C[M,N] = A[M,K] * Wq[N,K]^T  * gamma ----------------
__global__ __launch_bounds__(256) void gemm_bt(const u16* __restrict__ A,
                                               const u16* __restrict__ Bw,
                                               const double* __restrict__ sum,
                                               float* __restrict__ C) {
  __shared__ __align__(16) u16 As[BM * BK];
  __shared__ __align__(16) u16 Bs[BN * BK];

  int tid  = threadIdx.x;
  int lane = tid & 63;
  int wv   = tid >> 6;
  int wm   = (wv >> 1) * 64;   // wave row offset in tile
  int wn   = (wv & 1) * 64;    // wave col offset in tile
  int bm0  = blockIdx.y * BM;
  int bn0  = blockIdx.x * BN;
  int lm   = lane & 15;        // m (or n) within 16
  int kg   = lane >> 4;        // k-group 0..3

  f32x4 acc[4][4] = {};

  const u16* Ag = A  + (size_t)bm0 * D_INNER;
  const u16* Bg = Bw + (size_t)bn0 * D_INNER;

  for (int kt = 0; kt < D_INNER; kt += BK) {
    __syncthreads();   // previous compute done before overwriting LDS
#pragma unroll
    for (int r = 0; r < 4; ++r) {
      int ci = r * 256 + tid;
      int row = ci >> 3, kc = (ci & 7) << 3;
      __builtin_amdgcn_global_load_lds(
          (const __attribute__((address_space(1))) void*)(Ag + (size_t)row * D_INNER + kt + kc),
          (__attribute__((address_space(3))) void*)(As + ci * 8), 16, 0, 0);
    }
#pragma unroll
    for (int r = 0; r < 4; ++r) {
      int ci = r * 256 + tid;
      int row = ci >> 3, kc = (ci & 7) << 3;
      __builtin_amdgcn_global_load_lds(
          (const __attribute__((address_space(1))) void*)(Bg + (size_t)row * D_INNER + kt + kc),
          (__attribute__((address_space(3))) void*)(Bs + ci * 8), 16, 0, 0);
    }
    __syncthreads();   // compiler emits vmcnt(0) drain here

#pragma unroll
    for (int ks = 0; ks < BK; ks += 32) {
      bf16x8 af[4], bb[4];
#pragma unroll
      for (int i = 0; i < 4; ++i)
        af[i] = *(const bf16x8*)(As + (wm + i * 16 + lm) * BK + ks + kg * 8);
#pragma unroll
      for (int j = 0; j < 4; ++j)
        bb[j] = *(const bf16x8*)(Bs + (wn + j * 16 + lm) * BK + ks + kg * 8);
#pragma unroll
      for (int i = 0; i < 4; ++i)
#pragma unroll
        for (int j = 0; j < 4; ++j)
          acc[i][j] = __builtin_amdgcn_mfma_f32_16x16x32_bf16(af[i], bb[j], acc[i][j], 0, 0, 0);
    }
  }

  float gamma = (float)(*sum * (1.0 / (double)W_ELEMS));
#pragma unroll
  for (int i = 0; i < 4; ++i) {
    int row0 = bm0 + wm + i * 16 + kg * 4;   // C/D: row = (lane>>4)*4 + reg
#pragma unroll
    for (int j = 0; j < 4; ++j) {
      int col = bn0 + wn + j * 16 + lm;      // C/D: col = lane&15
      f32x4 v = acc[i][j];
#pragma unroll
      for (int r = 0; r < 4; ++r)
        C[(size_t)(row0 + r) * D_OUTER + col] = v[r] * gamma;
    }
  }
}

extern "C" void kernel_launch(void* const* d_in, const int* in_sizes, int n_in,
                              void* d_out, int out_size, void* d_ws, size_t ws_size,
                              hipStream_t stream) {
  const float* x = (const float*)d_in[0];   // [2,4096,2048]
  const float* w = (const float*)d_in[1];   // [2048,2048]
  const float* g = (const float*)d_in[2];   // [2048]
  float* out = (float*)d_out;               // [2,4096,2048] fp32

  double* sum = (double*)d_ws;
  u16* xn = (u16*)((char*)d_ws + 256);                                   // 32 MB
  u16* wq = (u16*)((char*)d_ws + 256 + (size_t)MROWS * D_INNER * 2);     // 8 MB

  hipMemsetAsync(d_ws, 0, 256, stream);
  absmean_kernel<<<1024, 256, 0, stream>>>(w, sum);
  quant_kernel<<<1024, 256, 0, stream>>>(w, sum, wq);
  rmsnorm_kernel<<<MROWS, 256, 0, stream>>>(x, g, xn);
  gemm_bt<<<dim3(D_OUTER / BN, MROWS / BM), 256, 0, stream>>>(xn, wq, sum, out);
}

// Round 2
// 217.045 us; speedup vs baseline: 1.0999x; 1.0999x over previous
//
#include <hip/hip_runtime.h>
#include <hip/hip_bf16.h>
#include <stdint.h>

typedef unsigned short u16;

#define D_INNER 2048
#define D_OUTER 2048
#define MROWS   8192                 // B*S = 2*4096
#define W_ELEMS (D_OUTER * D_INNER)  // 4194304

#define BM 128
#define BN 128
#define BK 64

typedef __attribute__((ext_vector_type(8))) __bf16 bf16x8;
typedef __attribute__((ext_vector_type(4))) float  f32x4;

__device__ __forceinline__ u16 f2bf(float f) {
  union { float f; unsigned u; } v; v.f = f;
  unsigned r = v.u + 0x7fff + ((v.u >> 16) & 1);   // RNE
  return (u16)(r >> 16);
}

// ---------------- 1) per-block |w| partial sums (no atomics, no memset) -------
__global__ void absmean_kernel(const float* __restrict__ w, float* __restrict__ partials) {
  int tid = blockIdx.x * blockDim.x + threadIdx.x;
  int stride = gridDim.x * blockDim.x;      // 256*256 = 65536
  float s = 0.f;
  for (int i = tid; i < W_ELEMS / 4; i += stride) {
    float4 v = ((const float4*)w)[i];
    s += fabsf(v.x) + fabsf(v.y) + fabsf(v.z) + fabsf(v.w);
  }
  for (int off = 32; off; off >>= 1) s += __shfl_down(s, off, 64);
  __shared__ float red[4];
  int lane = threadIdx.x & 63, wv = threadIdx.x >> 6;
  if (lane == 0) red[wv] = s;
  __syncthreads();
  if (threadIdx.x == 0) partials[blockIdx.x] = red[0] + red[1] + red[2] + red[3];
}

// ---------------- 2) ternary quantize -> bf16; block0 publishes gamma --------
__global__ void quant_kernel(const float* __restrict__ w, const float* __restrict__ partials,
                             float* __restrict__ gamma_out, u16* __restrict__ wq) {
  // every block re-reduces the 256 partials (deterministic, dependency-free)
  double d = (double)partials[threadIdx.x];   // blockDim.x == 256
  for (int off = 32; off; off >>= 1) d += __shfl_down(d, off, 64);
  __shared__ double red[4];
  int lane = threadIdx.x & 63, wv = threadIdx.x >> 6;
  if (lane == 0) red[wv] = d;
  __syncthreads();
  double total = red[0] + red[1] + red[2] + red[3];
  float gamma = (float)(total * (1.0 / (double)W_ELEMS));
  float inv = 1.0f / (gamma + 1e-8f);
  if (blockIdx.x == 0 && threadIdx.x == 0) *gamma_out = gamma;

  int tid = blockIdx.x * blockDim.x + threadIdx.x;
  int stride = gridDim.x * blockDim.x;
  for (int i = tid; i < W_ELEMS / 4; i += stride) {
    float4 v = ((const float4*)w)[i];
    ushort4 q;
    q.x = f2bf(fminf(1.f, fmaxf(-1.f, rintf(v.x * inv))));
    q.y = f2bf(fminf(1.f, fmaxf(-1.f, rintf(v.y * inv))));
    q.z = f2bf(fminf(1.f, fmaxf(-1.f, rintf(v.z * inv))));
    q.w = f2bf(fminf(1.f, fmaxf(-1.f, rintf(v.w * inv))));
    ((ushort4*)wq)[i] = q;
  }
}

// ---------------- 3) RMSNorm rows -> bf16 ----------------
__global__ void rmsnorm_kernel(const float* __restrict__ x, const float* __restrict__ g,
                               u16* __restrict__ xn) {
  int row = blockIdx.x;
  const float* xr = x + (size_t)row * D_INNER;
  u16* xo = xn + (size_t)row * D_INNER;
  int t = threadIdx.x;

  float4 v0 = ((const float4*)xr)[t * 2];
  float4 v1 = ((const float4*)xr)[t * 2 + 1];
  float s = v0.x * v0.x + v0.y * v0.y + v0.z * v0.z + v0.w * v0.w
          + v1.x * v1.x + v1.y * v1.y + v1.z * v1.z + v1.w * v1.w;
  for (int off = 32; off; off >>= 1) s += __shfl_down(s, off, 64);
  __shared__ float red[4];
  int lane = t & 63, wv = t >> 6;
  if (lane == 0) red[wv] = s;
  __syncthreads();
  float total = red[0] + red[1] + red[2] + red[3];
  float invr = 1.0f / sqrtf(total * (1.0f / (float)D_INNER) + 1e-6f);

  const float4* gr = (const float4*)g;
  float4 g0 = gr[t * 2], g1 = gr[t * 2 + 1];
  ushort4 o0, o1;
  o0.x = f2bf(v0.x * invr * g0.x); o0.y = f2bf(v0.y * invr * g0.y);
  o0.z = f2bf(v0.z * invr * g0.z); o0.w = f2bf(v0.w * invr * g0.w);
  o1.x = f2bf(v1.x * invr * g1.x); o1.y = f2bf(v1.y * invr * g1.y);
  o1.z = f2bf(v1.z * invr * g1.z); o1.w = f2bf(v1.w * invr * g1.w);
  ((ushort4*)xo)[t * 2] = o0;
  ((ushort4*)xo)[t * 2 + 1] = o1;
}

// ---------------- 4) GEMM  C[M,N] = A[M,K] * Wq[N,K]^T  * gamma ----------------
// LDS layout is XOR-swizzled: the 16B group g of row r lives at group (g ^ (r&7)).
// Staging achieves this by permuting the GLOBAL source per lane (the LDS side of
// global_load_lds is fixed to base+lane*16). Reads apply the same XOR -> each
// ds_read_b128 spreads the 64 lanes evenly over all 8 four-bank clusters.
__global__ __launch_bounds__(256) void gemm_bt(const u16* __restrict__ A,
                                               const u16* __restrict__ Bw,
                                               const float* __restrict__ gamma_p,
                                               float* __restrict__ C) {
  __shared__ __align__(16) u16 As[BM * BK];
  __shared__ __align__(16) u16 Bs[BN * BK];

  int tid  = threadIdx.x;
  int lane = tid & 63;
  int wv   = tid >> 6;
  int wm   = (wv >> 1) * 64;   // wave row offset in tile
  int wn   = (wv & 1) * 64;    // wave col offset in tile
  int bm0  = blockIdx.y * BM;
  int bn0  = blockIdx.x * BN;
  int lm   = lane & 15;        // m (or n) within 16
  int kg   = lane >> 4;        // k-group 0..3
  int sw   = lm & 7;           // read-side XOR swizzle (row&7 == lm&7 here)

  f32x4 acc[4][4] = {};

  const u16* Ag = A  + (size_t)bm0 * D_INNER;
  const u16* Bg = Bw + (size_t)bn0 * D_INNER;

  for (int kt = 0; kt < D_INNER; kt += BK) {
    __syncthreads();   // previous compute done before overwriting LDS
#pragma unroll
    for (int r = 0; r < 4; ++r) {
      int ci = r * 256 + tid;
      int row = ci >> 3;
      int kc = (((ci & 7) ^ (row & 7)) << 3);     // swizzled global group
      __builtin_amdgcn_global_load_lds(
          (const __attribute__((address_space(1))) void*)(Ag + (size_t)row * D_INNER + kt + kc),
          (__attribute__((address_space(3))) void*)(As + ci * 8), 16, 0, 0);
    }
#pragma unroll
    for (int r = 0; r < 4; ++r) {
      int ci = r * 256 + tid;
      int row = ci >> 3;
      int kc = (((ci & 7) ^ (row & 7)) << 3);
      __builtin_amdgcn_global_load_lds(
          (const __attribute__((address_space(1))) void*)(Bg + (size_t)row * D_INNER + kt + kc),
          (__attribute__((address_space(3))) void*)(Bs + ci * 8), 16, 0, 0);
    }
    __syncthreads();   // compiler emits vmcnt(0) drain here

#pragma unroll
    for (int ks = 0; ks < BK; ks += 32) {
      int g = (ks >> 3) + kg;                     // 16B group index before swizzle
      bf16x8 af[4], bb[4];
#pragma unroll
      for (int i = 0; i < 4; ++i)
        af[i] = *(const bf16x8*)(As + (wm + i * 16 + lm) * BK + ((g ^ sw) << 3));
#pragma unroll
      for (int j = 0; j < 4; ++j)
        bb[j] = *(const bf16x8*)(Bs + (wn + j * 16 + lm) * BK + ((g ^ sw) << 3));
#pragma unroll
      for (int i = 0; i < 4; ++i)
#pragma unroll
        for (int j = 0; j < 4; ++j)
          acc[i][j] = __builtin_amdgcn_mfma_f32_16x16x32_bf16(af[i], bb[j], acc[i][j], 0, 0, 0);
    }
  }

  float gamma = *gamma_p;
#pragma unroll
  for (int i = 0; i < 4; ++i) {
    int row0 = bm0 + wm + i * 16 + kg * 4;   // C/D: row = (lane>>4)*4 + reg
#pragma unroll
    for (int j = 0; j < 4; ++j) {
      int col = bn0 + wn + j * 16 + lm;      // C/D: col = lane&15
      f32x4 v = acc[i][j];
#pragma unroll
      for (int r = 0; r < 4; ++r)
        C[(size_t)(row0 + r) * D_OUTER + col] = v[r] * gamma;
    }
  }
}

extern "C" void kernel_launch(void* const* d_in, const int* in_sizes, int n_in,
                              void* d_out, int out_size, void* d_ws, size_t ws_size,
                              hipStream_t stream) {
  const float* x = (const float*)d_in[0];   // [2,4096,2048]
  const float* w = (const float*)d_in[1];   // [2048,2048]
  const float* g = (const float*)d_in[2];   // [2048]
  float* out = (float*)d_out;               // [2,4096,2048] fp32

  float* gamma_p  = (float*)d_ws;                                        // 1 float
  float* partials = (float*)((char*)d_ws + 64);                          // 256 floats
  u16* xn = (u16*)((char*)d_ws + 4096);                                  // 32 MB
  u16* wq = (u16*)((char*)d_ws + 4096 + (size_t)MROWS * D_INNER * 2);    // 8 MB

  absmean_kernel<<<256, 256, 0, stream>>>(w, partials);
  quant_kernel<<<256, 256, 0, stream>>>(w, partials, gamma_p, wq);
  rmsnorm_kernel<<<MROWS, 256, 0, stream>>>(x, g, xn);
  gemm_bt<<<dim3(D_OUTER / BN, MROWS / BM), 256, 0, stream>>>(xn, wq, gamma_p, out);
}

// Round 3
// 214.178 us; speedup vs baseline: 1.1146x; 1.0134x over previous
//
#include <hip/hip_runtime.h>
#include <hip/hip_bf16.h>
#include <stdint.h>

typedef unsigned short u16;

#define D_INNER 2048
#define D_OUTER 2048
#define MROWS   8192                 // B*S = 2*4096
#define W_ELEMS (D_OUTER * D_INNER)  // 4194304

#define BM 128
#define BN 128
#define BK 64

typedef __attribute__((ext_vector_type(8))) __bf16 bf16x8;
typedef __attribute__((ext_vector_type(4))) float  f32x4;

__device__ __forceinline__ u16 f2bf(float f) {
  union { float f; unsigned u; } v; v.f = f;
  unsigned r = v.u + 0x7fff + ((v.u >> 16) & 1);   // RNE
  return (u16)(r >> 16);
}

// ------- 1) fused prep: blocks [0,8192) = RMSNorm rows; [8192,8448) = |w| partials
__global__ void prep_kernel(const float* __restrict__ x, const float* __restrict__ g,
                            const float* __restrict__ w,
                            u16* __restrict__ xn, float* __restrict__ partials) {
  __shared__ float red[4];
  int t = threadIdx.x;
  int lane = t & 63, wvi = t >> 6;

  if (blockIdx.x >= MROWS) {
    // ---- absmean partial for block p ----
    int p = blockIdx.x - MROWS;
    int tid = p * 256 + t;
    int stride = 256 * 256;
    float s = 0.f;
    for (int i = tid; i < W_ELEMS / 4; i += stride) {
      float4 v = ((const float4*)w)[i];
      s += fabsf(v.x) + fabsf(v.y) + fabsf(v.z) + fabsf(v.w);
    }
    for (int off = 32; off; off >>= 1) s += __shfl_down(s, off, 64);
    if (lane == 0) red[wvi] = s;
    __syncthreads();
    if (t == 0) partials[p] = red[0] + red[1] + red[2] + red[3];
    return;
  }

  // ---- RMSNorm one row ----
  int row = blockIdx.x;
  const float* xr = x + (size_t)row * D_INNER;
  u16* xo = xn + (size_t)row * D_INNER;

  float4 v0 = ((const float4*)xr)[t * 2];
  float4 v1 = ((const float4*)xr)[t * 2 + 1];
  float s = v0.x * v0.x + v0.y * v0.y + v0.z * v0.z + v0.w * v0.w
          + v1.x * v1.x + v1.y * v1.y + v1.z * v1.z + v1.w * v1.w;
  for (int off = 32; off; off >>= 1) s += __shfl_down(s, off, 64);
  if (lane == 0) red[wvi] = s;
  __syncthreads();
  float total = red[0] + red[1] + red[2] + red[3];
  float invr = 1.0f / sqrtf(total * (1.0f / (float)D_INNER) + 1e-6f);

  const float4* gr = (const float4*)g;
  float4 g0 = gr[t * 2], g1 = gr[t * 2 + 1];
  ushort4 o0, o1;
  o0.x = f2bf(v0.x * invr * g0.x); o0.y = f2bf(v0.y * invr * g0.y);
  o0.z = f2bf(v0.z * invr * g0.z); o0.w = f2bf(v0.w * invr * g0.w);
  o1.x = f2bf(v1.x * invr * g1.x); o1.y = f2bf(v1.y * invr * g1.y);
  o1.z = f2bf(v1.z * invr * g1.z); o1.w = f2bf(v1.w * invr * g1.w);
  ((ushort4*)xo)[t * 2] = o0;
  ((ushort4*)xo)[t * 2 + 1] = o1;
}

// ------- 2) ternary quantize -> bf16; block0 publishes gamma -------
__global__ void quant_kernel(const float* __restrict__ w, const float* __restrict__ partials,
                             float* __restrict__ gamma_out, u16* __restrict__ wq) {
  double d = (double)partials[threadIdx.x];   // blockDim.x == 256
  for (int off = 32; off; off >>= 1) d += __shfl_down(d, off, 64);
  __shared__ double red[4];
  int lane = threadIdx.x & 63, wvi = threadIdx.x >> 6;
  if (lane == 0) red[wvi] = d;
  __syncthreads();
  double total = red[0] + red[1] + red[2] + red[3];
  float gamma = (float)(total * (1.0 / (double)W_ELEMS));
  float inv = 1.0f / (gamma + 1e-8f);
  if (blockIdx.x == 0 && threadIdx.x == 0) *gamma_out = gamma;

  int tid = blockIdx.x * blockDim.x + threadIdx.x;
  int stride = gridDim.x * blockDim.x;
  for (int i = tid; i < W_ELEMS / 4; i += stride) {
    float4 v = ((const float4*)w)[i];
    ushort4 q;
    q.x = f2bf(fminf(1.f, fmaxf(-1.f, rintf(v.x * inv))));
    q.y = f2bf(fminf(1.f, fmaxf(-1.f, rintf(v.y * inv))));
    q.z = f2bf(fminf(1.f, fmaxf(-1.f, rintf(v.z * inv))));
    q.w = f2bf(fminf(1.f, fmaxf(-1.f, rintf(v.w * inv))));
    ((ushort4*)wq)[i] = q;
  }
}

// ------- 3) GEMM  C[M,N] = A[M,K] * Wq[N,K]^T * gamma -------
// LDS XOR-swizzled (conflict-free b128 reads). Grid remapped XCD-aware:
// xcd = f&7 (dispatch round-robin heuristic); each XCD owns one N-half
// (8 panels * 512KB = 4MB = its L2) and sweeps it N-fastest, so B stays
// L2-resident and the pre-barrier vmcnt drain pays L2 latency, not L3.
__global__ __launch_bounds__(256) void gemm_bt(const u16* __restrict__ A,
                                               const u16* __restrict__ Bw,
                                               const float* __restrict__ gamma_p,
                                               float* __restrict__ C) {
  __shared__ __align__(16) u16 As[BM * BK];
  __shared__ __align__(16) u16 Bs[BN * BK];

  int f   = blockIdx.y * 16 + blockIdx.x;   // x-fastest dispatch order, 0..1023
  int xcd = f & 7;
  int gg  = f >> 3;                         // 0..127
  int nb  = (xcd >> 2) * 8 + (gg & 7);      // 0..15  (XCD-group owns an N-half)
  int mb  = (gg >> 3) * 4 + (xcd & 3);      // 0..63  (A tile hot across 8 n-steps)
  int bm0 = mb * BM;
  int bn0 = nb * BN;

  int tid  = threadIdx.x;
  int lane = tid & 63;
  int wv   = tid >> 6;
  int wm   = (wv >> 1) * 64;   // wave row offset in tile
  int wn   = (wv & 1) * 64;    // wave col offset in tile
  int lm   = lane & 15;        // m (or n) within 16
  int kg   = lane >> 4;        // k-group 0..3
  int sw   = lm & 7;           // read-side XOR swizzle (row&7 == lm&7 here)

  f32x4 acc[4][4] = {};

  const u16* Ag = A  + (size_t)bm0 * D_INNER;
  const u16* Bg = Bw + (size_t)bn0 * D_INNER;

  for (int kt = 0; kt < D_INNER; kt += BK) {
    __syncthreads();   // previous compute done before overwriting LDS
#pragma unroll
    for (int r = 0; r < 4; ++r) {
      int ci = r * 256 + tid;
      int row = ci >> 3;
      int kc = (((ci & 7) ^ (row & 7)) << 3);     // swizzled global group
      __builtin_amdgcn_global_load_lds(
          (const __attribute__((address_space(1))) void*)(Ag + (size_t)row * D_INNER + kt + kc),
          (__attribute__((address_space(3))) void*)(As + ci * 8), 16, 0, 0);
    }
#pragma unroll
    for (int r = 0; r < 4; ++r) {
      int ci = r * 256 + tid;
      int row = ci >> 3;
      int kc = (((ci & 7) ^ (row & 7)) << 3);
      __builtin_amdgcn_global_load_lds(
          (const __attribute__((address_space(1))) void*)(Bg + (size_t)row * D_INNER + kt + kc),
          (__attribute__((address_space(3))) void*)(Bs + ci * 8), 16, 0, 0);
    }
    __syncthreads();   // compiler emits vmcnt(0) drain here

#pragma unroll
    for (int ks = 0; ks < BK; ks += 32) {
      int g = (ks >> 3) + kg;                     // 16B group index before swizzle
      bf16x8 af[4], bb[4];
#pragma unroll
      for (int i = 0; i < 4; ++i)
        af[i] = *(const bf16x8*)(As + (wm + i * 16 + lm) * BK + ((g ^ sw) << 3));
#pragma unroll
      for (int j = 0; j < 4; ++j)
        bb[j] = *(const bf16x8*)(Bs + (wn + j * 16 + lm) * BK + ((g ^ sw) << 3));
#pragma unroll
      for (int i = 0; i < 4; ++i)
#pragma unroll
        for (int j = 0; j < 4; ++j)
          acc[i][j] = __builtin_amdgcn_mfma_f32_16x16x32_bf16(af[i], bb[j], acc[i][j], 0, 0, 0);
    }
  }

  float gamma = *gamma_p;
#pragma unroll
  for (int i = 0; i < 4; ++i) {
    int row0 = bm0 + wm + i * 16 + kg * 4;   // C/D: row = (lane>>4)*4 + reg
#pragma unroll
    for (int j = 0; j < 4; ++j) {
      int col = bn0 + wn + j * 16 + lm;      // C/D: col = lane&15
      f32x4 v = acc[i][j];
#pragma unroll
      for (int r = 0; r < 4; ++r)
        C[(size_t)(row0 + r) * D_OUTER + col] = v[r] * gamma;
    }
  }
}

extern "C" void kernel_launch(void* const* d_in, const int* in_sizes, int n_in,
                              void* d_out, int out_size, void* d_ws, size_t ws_size,
                              hipStream_t stream) {
  const float* x = (const float*)d_in[0];   // [2,4096,2048]
  const float* w = (const float*)d_in[1];   // [2048,2048]
  const float* g = (const float*)d_in[2];   // [2048]
  float* out = (float*)d_out;               // [2,4096,2048] fp32

  float* gamma_p  = (float*)d_ws;                                        // 1 float
  float* partials = (float*)((char*)d_ws + 64);                          // 256 floats
  u16* xn = (u16*)((char*)d_ws + 4096);                                  // 32 MB
  u16* wq = (u16*)((char*)d_ws + 4096 + (size_t)MROWS * D_INNER * 2);    // 8 MB

  prep_kernel<<<MROWS + 256, 256, 0, stream>>>(x, g, w, xn, partials);
  quant_kernel<<<256, 256, 0, stream>>>(w, partials, gamma_p, wq);
  gemm_bt<<<dim3(D_OUTER / BN, MROWS / BM), 256, 0, stream>>>(xn, wq, gamma_p, out);
}

// Round 5
// 209.948 us; speedup vs baseline: 1.1370x; 1.0201x over previous
//
#include <hip/hip_runtime.h>
#include <hip/hip_bf16.h>
#include <stdint.h>

typedef unsigned short u16;

#define D_INNER 2048
#define D_OUTER 2048
#define MROWS   8192                 // B*S = 2*4096
#define W_ELEMS (D_OUTER * D_INNER)  // 4194304
#define NPART   1024                 // absmean partial blocks (each covers 1024 float4)

#define BM 128
#define BN 128
#define BK 64

typedef __attribute__((ext_vector_type(8))) __bf16 bf16x8;
typedef __attribute__((ext_vector_type(4))) float  f32x4;
typedef __attribute__((ext_vector_type(4))) u16    u16x4;

__device__ __forceinline__ u16 f2bf(float f) {
  union { float f; unsigned u; } v; v.f = f;
  unsigned r = v.u + 0x7fff + ((v.u >> 16) & 1);   // RNE
  return (u16)(r >> 16);
}

// ------- 1) fused prep: blocks [0,8192) = RMSNorm rows; [8192,8192+1024) = |w| partials
__global__ __launch_bounds__(256) void prep_kernel(const float* __restrict__ x,
                            const float* __restrict__ g,
                            const float* __restrict__ w,
                            u16* __restrict__ xn, float* __restrict__ partials) {
  __shared__ float red[4];
  int t = threadIdx.x;
  int lane = t & 63, wvi = t >> 6;

  if (blockIdx.x >= MROWS) {
    // ---- absmean partial: 4 float4 per thread, block covers 1024 float4 ----
    // 1024 blocks * 1024 float4 = 1048576 = W_ELEMS/4 (full coverage!)
    int p = blockIdx.x - MROWS;                    // 0..1023
    int base = p * 1024;
    float s = 0.f;
#pragma unroll
    for (int r = 0; r < 4; ++r) {
      f32x4 v = ((const f32x4*)w)[base + r * 256 + t];
      s += fabsf(v[0]) + fabsf(v[1]) + fabsf(v[2]) + fabsf(v[3]);
    }
    for (int off = 32; off; off >>= 1) s += __shfl_down(s, off, 64);
    if (lane == 0) red[wvi] = s;
    __syncthreads();
    if (t == 0) partials[p] = red[0] + red[1] + red[2] + red[3];
    return;
  }

  // ---- RMSNorm one row: coalesced [t], [t+256] float4 loads ----
  int row = blockIdx.x;
  const f32x4* xr = (const f32x4*)(x + (size_t)row * D_INNER);   // 512 float4/row
  u16x4* xo = (u16x4*)(xn + (size_t)row * D_INNER);              // 512 u16x4/row

  f32x4 v0 = __builtin_nontemporal_load(&xr[t]);
  f32x4 v1 = __builtin_nontemporal_load(&xr[t + 256]);
  float s = v0[0]*v0[0] + v0[1]*v0[1] + v0[2]*v0[2] + v0[3]*v0[3]
          + v1[0]*v1[0] + v1[1]*v1[1] + v1[2]*v1[2] + v1[3]*v1[3];
  for (int off = 32; off; off >>= 1) s += __shfl_down(s, off, 64);
  if (lane == 0) red[wvi] = s;
  __syncthreads();
  float total = red[0] + red[1] + red[2] + red[3];
  float invr = 1.0f / sqrtf(total * (1.0f / (float)D_INNER) + 1e-6f);

  const f32x4* gr = (const f32x4*)g;
  f32x4 g0 = gr[t], g1 = gr[t + 256];
  u16x4 o0, o1;
  o0[0] = f2bf(v0[0] * invr * g0[0]); o0[1] = f2bf(v0[1] * invr * g0[1]);
  o0[2] = f2bf(v0[2] * invr * g0[2]); o0[3] = f2bf(v0[3] * invr * g0[3]);
  o1[0] = f2bf(v1[0] * invr * g1[0]); o1[1] = f2bf(v1[1] * invr * g1[1]);
  o1[2] = f2bf(v1[2] * invr * g1[2]); o1[3] = f2bf(v1[3] * invr * g1[3]);
  xo[t] = o0;
  xo[t + 256] = o1;
}

// ------- 2) ternary quantize -> bf16; block0 publishes gamma -------
__global__ __launch_bounds__(256) void quant_kernel(const float* __restrict__ w,
                             const float* __restrict__ partials,
                             float* __restrict__ gamma_out, u16* __restrict__ wq) {
  // every block re-reduces the 1024 partials (one float4/thread; deterministic)
  f32x4 pv = ((const f32x4*)partials)[threadIdx.x];
  double d = (double)pv[0] + (double)pv[1] + (double)pv[2] + (double)pv[3];
  for (int off = 32; off; off >>= 1) d += __shfl_down(d, off, 64);
  __shared__ double red[4];
  int lane = threadIdx.x & 63, wvi = threadIdx.x >> 6;
  if (lane == 0) red[wvi] = d;
  __syncthreads();
  double total = red[0] + red[1] + red[2] + red[3];
  float gamma = (float)(total * (1.0 / (double)W_ELEMS));
  float inv = 1.0f / (gamma + 1e-8f);
  if (blockIdx.x == 0 && threadIdx.x == 0) *gamma_out = gamma;

  int tid = blockIdx.x * blockDim.x + threadIdx.x;
  int stride = gridDim.x * blockDim.x;               // 2048*256 -> 2 iterations
  for (int i = tid; i < W_ELEMS / 4; i += stride) {
    f32x4 v = ((const f32x4*)w)[i];
    u16x4 q;
    q[0] = f2bf(fminf(1.f, fmaxf(-1.f, rintf(v[0] * inv))));
    q[1] = f2bf(fminf(1.f, fmaxf(-1.f, rintf(v[1] * inv))));
    q[2] = f2bf(fminf(1.f, fmaxf(-1.f, rintf(v[2] * inv))));
    q[3] = f2bf(fminf(1.f, fmaxf(-1.f, rintf(v[3] * inv))));
    ((u16x4*)wq)[i] = q;
  }
}

// ------- 3) GEMM  C[M,N] = A[M,K] * Wq[N,K]^T * gamma -------
// LDS XOR-swizzled (conflict-free b128 reads). XCD-aware grid remap keeps each
// XCD's B half (4MB) L2-resident. C stores are nontemporal so the 64MB of dead
// writes don't thrash the B panels out of L2.
__global__ __launch_bounds__(256) void gemm_bt(const u16* __restrict__ A,
                                               const u16* __restrict__ Bw,
                                               const float* __restrict__ gamma_p,
                                               float* __restrict__ C) {
  __shared__ __align__(16) u16 As[BM * BK];
  __shared__ __align__(16) u16 Bs[BN * BK];

  int f   = blockIdx.y * 16 + blockIdx.x;   // x-fastest dispatch order, 0..1023
  int xcd = f & 7;
  int gg  = f >> 3;                         // 0..127
  int nb  = (xcd >> 2) * 8 + (gg & 7);      // 0..15  (XCD-group owns an N-half)
  int mb  = (gg >> 3) * 4 + (xcd & 3);      // 0..63  (A tile hot across 8 n-steps)
  int bm0 = mb * BM;
  int bn0 = nb * BN;

  int tid  = threadIdx.x;
  int lane = tid & 63;
  int wv   = tid >> 6;
  int wm   = (wv >> 1) * 64;   // wave row offset in tile
  int wn   = (wv & 1) * 64;    // wave col offset in tile
  int lm   = lane & 15;        // m (or n) within 16
  int kg   = lane >> 4;        // k-group 0..3
  int sw   = lm & 7;           // read-side XOR swizzle (row&7 == lm&7 here)

  f32x4 acc[4][4] = {};

  const u16* Ag = A  + (size_t)bm0 * D_INNER;
  const u16* Bg = Bw + (size_t)bn0 * D_INNER;

  for (int kt = 0; kt < D_INNER; kt += BK) {
    __syncthreads();   // previous compute done before overwriting LDS
#pragma unroll
    for (int r = 0; r < 4; ++r) {
      int ci = r * 256 + tid;
      int row = ci >> 3;
      int kc = (((ci & 7) ^ (row & 7)) << 3);     // swizzled global group
      __builtin_amdgcn_global_load_lds(
          (const __attribute__((address_space(1))) void*)(Ag + (size_t)row * D_INNER + kt + kc),
          (__attribute__((address_space(3))) void*)(As + ci * 8), 16, 0, 0);
    }
#pragma unroll
    for (int r = 0; r < 4; ++r) {
      int ci = r * 256 + tid;
      int row = ci >> 3;
      int kc = (((ci & 7) ^ (row & 7)) << 3);
      __builtin_amdgcn_global_load_lds(
          (const __attribute__((address_space(1))) void*)(Bg + (size_t)row * D_INNER + kt + kc),
          (__attribute__((address_space(3))) void*)(Bs + ci * 8), 16, 0, 0);
    }
    __syncthreads();   // compiler emits vmcnt(0) drain here

#pragma unroll
    for (int ks = 0; ks < BK; ks += 32) {
      int g = (ks >> 3) + kg;                     // 16B group index before swizzle
      bf16x8 af[4], bb[4];
#pragma unroll
      for (int i = 0; i < 4; ++i)
        af[i] = *(const bf16x8*)(As + (wm + i * 16 + lm) * BK + ((g ^ sw) << 3));
#pragma unroll
      for (int j = 0; j < 4; ++j)
        bb[j] = *(const bf16x8*)(Bs + (wn + j * 16 + lm) * BK + ((g ^ sw) << 3));
#pragma unroll
      for (int i = 0; i < 4; ++i)
#pragma unroll
        for (int j = 0; j < 4; ++j)
          acc[i][j] = __builtin_amdgcn_mfma_f32_16x16x32_bf16(af[i], bb[j], acc[i][j], 0, 0, 0);
    }
  }

  float gamma = *gamma_p;
#pragma unroll
  for (int i = 0; i < 4; ++i) {
    int row0 = bm0 + wm + i * 16 + kg * 4;   // C/D: row = (lane>>4)*4 + reg
#pragma unroll
    for (int j = 0; j < 4; ++j) {
      int col = bn0 + wn + j * 16 + lm;      // C/D: col = lane&15
      f32x4 v = acc[i][j];
#pragma unroll
      for (int r = 0; r < 4; ++r)
        __builtin_nontemporal_store(v[r] * gamma, &C[(size_t)(row0 + r) * D_OUTER + col]);
    }
  }
}

extern "C" void kernel_launch(void* const* d_in, const int* in_sizes, int n_in,
                              void* d_out, int out_size, void* d_ws, size_t ws_size,
                              hipStream_t stream) {
  const float* x = (const float*)d_in[0];   // [2,4096,2048]
  const float* w = (const float*)d_in[1];   // [2048,2048]
  const float* g = (const float*)d_in[2];   // [2048]
  float* out = (float*)d_out;               // [2,4096,2048] fp32

  float* gamma_p  = (float*)d_ws;                                        // 1 float
  float* partials = (float*)((char*)d_ws + 64);                          // 1024 floats
  u16* xn = (u16*)((char*)d_ws + 8192);                                  // 32 MB
  u16* wq = (u16*)((char*)d_ws + 8192 + (size_t)MROWS * D_INNER * 2);    // 8 MB

  prep_kernel<<<MROWS + NPART, 256, 0, stream>>>(x, g, w, xn, partials);
  quant_kernel<<<2048, 256, 0, stream>>>(w, partials, gamma_p, wq);
  gemm_bt<<<dim3(D_OUTER / BN, MROWS / BM), 256, 0, stream>>>(xn, wq, gamma_p, out);
}

// Round 6
// 169.358 us; speedup vs baseline: 1.4095x; 1.2397x over previous
//
#include <hip/hip_runtime.h>
#include <hip/hip_bf16.h>
#include <stdint.h>

typedef unsigned short u16;
typedef signed char i8;

#define D_INNER 2048
#define D_OUTER 2048
#define MROWS   8192                 // B*S = 2*4096
#define W_ELEMS (D_OUTER * D_INNER)  // 4194304
#define NPART   1024                 // absmean partial blocks (each covers 1024 float4)

#define BM 128
#define BN 128
#define BK 128                       // i8 elements per K-tile (= 128 bytes/row, 8 16B groups)

typedef __attribute__((ext_vector_type(4))) float f32x4;
typedef __attribute__((ext_vector_type(4))) int   i32x4;

// ------- 1) fused prep: blocks [0,8192) = RMSNorm rows -> i8 + per-row step;
//            blocks [8192,8192+1024) = |w| partials
__global__ __launch_bounds__(256) void prep_kernel(const float* __restrict__ x,
                            const float* __restrict__ g,
                            const float* __restrict__ w,
                            i8* __restrict__ xn, float* __restrict__ srow,
                            float* __restrict__ partials) {
  __shared__ float red[4];
  __shared__ float redm[4];
  int t = threadIdx.x;
  int lane = t & 63, wvi = t >> 6;

  if (blockIdx.x >= MROWS) {
    // ---- absmean partial: 4 float4/thread, 1024 blocks * 1024 float4 = full W ----
    int p = blockIdx.x - MROWS;                    // 0..1023
    int base = p * 1024;
    float s = 0.f;
#pragma unroll
    for (int r = 0; r < 4; ++r) {
      f32x4 v = ((const f32x4*)w)[base + r * 256 + t];
      s += fabsf(v[0]) + fabsf(v[1]) + fabsf(v[2]) + fabsf(v[3]);
    }
    for (int off = 32; off; off >>= 1) s += __shfl_down(s, off, 64);
    if (lane == 0) red[wvi] = s;
    __syncthreads();
    if (t == 0) partials[p] = red[0] + red[1] + red[2] + red[3];
    return;
  }

  // ---- RMSNorm one row -> per-row i8 quantization ----
  int row = blockIdx.x;
  const f32x4* xr = (const f32x4*)(x + (size_t)row * D_INNER);   // 512 float4/row
  i8* xo = xn + (size_t)row * D_INNER;

  f32x4 v0 = __builtin_nontemporal_load(&xr[t]);
  f32x4 v1 = __builtin_nontemporal_load(&xr[t + 256]);
  const f32x4* gr = (const f32x4*)g;
  f32x4 g0 = gr[t], g1 = gr[t + 256];

  float s = v0[0]*v0[0] + v0[1]*v0[1] + v0[2]*v0[2] + v0[3]*v0[3]
          + v1[0]*v1[0] + v1[1]*v1[1] + v1[2]*v1[2] + v1[3]*v1[3];
  float m = fmaxf(fmaxf(fmaxf(fabsf(v0[0]*g0[0]), fabsf(v0[1]*g0[1])),
                        fmaxf(fabsf(v0[2]*g0[2]), fabsf(v0[3]*g0[3]))),
                  fmaxf(fmaxf(fabsf(v1[0]*g1[0]), fabsf(v1[1]*g1[1])),
                        fmaxf(fabsf(v1[2]*g1[2]), fabsf(v1[3]*g1[3]))));
  for (int off = 32; off; off >>= 1) {
    s += __shfl_down(s, off, 64);
    m = fmaxf(m, __shfl_down(m, off, 64));
  }
  if (lane == 0) { red[wvi] = s; redm[wvi] = m; }
  __syncthreads();
  float total = red[0] + red[1] + red[2] + red[3];
  float rmax  = fmaxf(fmaxf(redm[0], redm[1]), fmaxf(redm[2], redm[3]));
  float invr = 1.0f / sqrtf(total * (1.0f / (float)D_INNER) + 1e-6f);

  float amax = fmaxf(rmax * invr, 1e-12f);   // max |xn| this row
  float step = amax * (1.0f / 127.0f);       // dequant step
  float qs   = 127.0f / amax;                // quant scale
  if (t == 0) srow[row] = step;

  char4 q0, q1;
  float qv;
  qv = fminf(127.f, fmaxf(-127.f, rintf(v0[0]*invr*g0[0]*qs))); q0.x = (i8)(int)qv;
  qv = fminf(127.f, fmaxf(-127.f, rintf(v0[1]*invr*g0[1]*qs))); q0.y = (i8)(int)qv;
  qv = fminf(127.f, fmaxf(-127.f, rintf(v0[2]*invr*g0[2]*qs))); q0.z = (i8)(int)qv;
  qv = fminf(127.f, fmaxf(-127.f, rintf(v0[3]*invr*g0[3]*qs))); q0.w = (i8)(int)qv;
  qv = fminf(127.f, fmaxf(-127.f, rintf(v1[0]*invr*g1[0]*qs))); q1.x = (i8)(int)qv;
  qv = fminf(127.f, fmaxf(-127.f, rintf(v1[1]*invr*g1[1]*qs))); q1.y = (i8)(int)qv;
  qv = fminf(127.f, fmaxf(-127.f, rintf(v1[2]*invr*g1[2]*qs))); q1.z = (i8)(int)qv;
  qv = fminf(127.f, fmaxf(-127.f, rintf(v1[3]*invr*g1[3]*qs))); q1.w = (i8)(int)qv;
  ((char4*)xo)[t]       = q0;
  ((char4*)xo)[t + 256] = q1;
}

// ------- 2) ternary quantize -> i8; block0 publishes gamma -------
__global__ __launch_bounds__(256) void quant_kernel(const float* __restrict__ w,
                             const float* __restrict__ partials,
                             float* __restrict__ gamma_out, i8* __restrict__ wq) {
  // every block re-reduces the 1024 partials (one float4/thread; deterministic)
  f32x4 pv = ((const f32x4*)partials)[threadIdx.x];
  double d = (double)pv[0] + (double)pv[1] + (double)pv[2] + (double)pv[3];
  for (int off = 32; off; off >>= 1) d += __shfl_down(d, off, 64);
  __shared__ double red[4];
  int lane = threadIdx.x & 63, wvi = threadIdx.x >> 6;
  if (lane == 0) red[wvi] = d;
  __syncthreads();
  double total = red[0] + red[1] + red[2] + red[3];
  float gamma = (float)(total * (1.0 / (double)W_ELEMS));
  float inv = 1.0f / (gamma + 1e-8f);
  if (blockIdx.x == 0 && threadIdx.x == 0) *gamma_out = gamma;

  int tid = blockIdx.x * blockDim.x + threadIdx.x;
  int stride = gridDim.x * blockDim.x;               // 2048*256 -> 2 iterations
  for (int i = tid; i < W_ELEMS / 4; i += stride) {
    f32x4 v = ((const f32x4*)w)[i];
    char4 q;
    q.x = (i8)(int)fminf(1.f, fmaxf(-1.f, rintf(v[0] * inv)));
    q.y = (i8)(int)fminf(1.f, fmaxf(-1.f, rintf(v[1] * inv)));
    q.z = (i8)(int)fminf(1.f, fmaxf(-1.f, rintf(v[2] * inv)));
    q.w = (i8)(int)fminf(1.f, fmaxf(-1.f, rintf(v[3] * inv)));
    ((char4*)wq)[i] = q;
  }
}

// ------- 3) i8 GEMM  C[M,N] = (qA[M,K] * Wq[N,K]^T) * gamma * step_row -------
// i32 accumulation is exact; 16x16x64 i8 MFMA = 2x bf16 rate; BK=128 i8 covers
// 2x the K per tile at the same 16KB LDS / staging volume. XOR swizzle identical
// (row = 128B = 8 16B-groups). XCD-aware remap keeps each XCD's B half (2MB)
// L2-resident.
__global__ __launch_bounds__(256) void gemm_bt(const i8* __restrict__ A,
                                               const i8* __restrict__ Bw,
                                               const float* __restrict__ gamma_p,
                                               const float* __restrict__ srow,
                                               float* __restrict__ C) {
  __shared__ __align__(16) i8 As[BM * BK];   // 16 KB
  __shared__ __align__(16) i8 Bs[BN * BK];   // 16 KB

  int f   = blockIdx.y * 16 + blockIdx.x;   // x-fastest dispatch order, 0..1023
  int xcd = f & 7;
  int gg  = f >> 3;                         // 0..127
  int nb  = (xcd >> 2) * 8 + (gg & 7);      // 0..15  (XCD-group owns an N-half)
  int mb  = (gg >> 3) * 4 + (xcd & 3);      // 0..63  (A tile hot across 8 n-steps)
  int bm0 = mb * BM;
  int bn0 = nb * BN;

  int tid  = threadIdx.x;
  int lane = tid & 63;
  int wv   = tid >> 6;
  int wm   = (wv >> 1) * 64;   // wave row offset in tile
  int wn   = (wv & 1) * 64;    // wave col offset in tile
  int lm   = lane & 15;        // m (or n) within 16
  int kg   = lane >> 4;        // k-group 0..3
  int sw   = lm & 7;           // read-side XOR swizzle (row&7 == lm&7 here)

  i32x4 acc[4][4] = {};

  const i8* Ag = A  + (size_t)bm0 * D_INNER;
  const i8* Bg = Bw + (size_t)bn0 * D_INNER;

  for (int kt = 0; kt < D_INNER; kt += BK) {   // 16 iterations
    __syncthreads();   // previous compute done before overwriting LDS
#pragma unroll
    for (int r = 0; r < 4; ++r) {
      int ci = r * 256 + tid;                      // 0..1023 16B-chunks
      int row = ci >> 3;                           // 8 chunks per 128B row
      int kc = (((ci & 7) ^ (row & 7)) << 4);      // swizzled byte offset in row
      __builtin_amdgcn_global_load_lds(
          (const __attribute__((address_space(1))) void*)(Ag + (size_t)row * D_INNER + kt + kc),
          (__attribute__((address_space(3))) void*)(As + ci * 16), 16, 0, 0);
    }
#pragma unroll
    for (int r = 0; r < 4; ++r) {
      int ci = r * 256 + tid;
      int row = ci >> 3;
      int kc = (((ci & 7) ^ (row & 7)) << 4);
      __builtin_amdgcn_global_load_lds(
          (const __attribute__((address_space(1))) void*)(Bg + (size_t)row * D_INNER + kt + kc),
          (__attribute__((address_space(3))) void*)(Bs + ci * 16), 16, 0, 0);
    }
    __syncthreads();   // vmcnt(0) drain

#pragma unroll
    for (int s = 0; s < 2; ++s) {                 // two K=64 MFMA steps per tile
      int gsel = s * 4 + kg;                      // 16B group index before swizzle
      i32x4 af[4], bb[4];
#pragma unroll
      for (int i = 0; i < 4; ++i)
        af[i] = *(const i32x4*)(As + (wm + i * 16 + lm) * BK + ((gsel ^ sw) << 4));
#pragma unroll
      for (int j = 0; j < 4; ++j)
        bb[j] = *(const i32x4*)(Bs + (wn + j * 16 + lm) * BK + ((gsel ^ sw) << 4));
#pragma unroll
      for (int i = 0; i < 4; ++i)
#pragma unroll
        for (int j = 0; j < 4; ++j)
          acc[i][j] = __builtin_amdgcn_mfma_i32_16x16x64_i8(af[i], bb[j], acc[i][j], 0, 0, 0);
    }
  }

  float gamma = *gamma_p;
#pragma unroll
  for (int i = 0; i < 4; ++i) {
    int row0 = bm0 + wm + i * 16 + kg * 4;           // C/D: row = (lane>>4)*4 + reg
    f32x4 sv = *(const f32x4*)(srow + row0);         // 4 contiguous row steps, 16B aligned
#pragma unroll
    for (int j = 0; j < 4; ++j) {
      int col = bn0 + wn + j * 16 + lm;              // C/D: col = lane&15
      i32x4 v = acc[i][j];
#pragma unroll
      for (int r = 0; r < 4; ++r)
        C[(size_t)(row0 + r) * D_OUTER + col] = (float)v[r] * gamma * sv[r];
    }
  }
}

extern "C" void kernel_launch(void* const* d_in, const int* in_sizes, int n_in,
                              void* d_out, int out_size, void* d_ws, size_t ws_size,
                              hipStream_t stream) {
  const float* x = (const float*)d_in[0];   // [2,4096,2048]
  const float* w = (const float*)d_in[1];   // [2048,2048]
  const float* g = (const float*)d_in[2];   // [2048]
  float* out = (float*)d_out;               // [2,4096,2048] fp32

  float* gamma_p  = (float*)d_ws;                                  // 1 float
  float* partials = (float*)((char*)d_ws + 64);                    // 1024 floats
  float* srow     = (float*)((char*)d_ws + 8192);                  // 8192 floats (32 KB)
  i8* xn = (i8*)((char*)d_ws + 8192 + 32768);                      // 16 MB
  i8* wq = (i8*)((char*)d_ws + 8192 + 32768 + (size_t)MROWS * D_INNER);  // 4 MB

  prep_kernel<<<MROWS + NPART, 256, 0, stream>>>(x, g, w, xn, srow, partials);
  quant_kernel<<<2048, 256, 0, stream>>>(w, partials, gamma_p, wq);
  gemm_bt<<<dim3(D_OUTER / BN, MROWS / BM), 256, 0, stream>>>(xn, wq, gamma_p, srow, out);
}